// Round 3
// baseline (114.104 us; speedup 1.0000x reference)
//
#include <hip/hip_runtime.h>
#include <math.h>

#define NN 8192
#define CC 256
#define LOG2N 13

typedef float f32x4 __attribute__((ext_vector_type(4)));

// ---------------- ws layout (floats) ----------------
// aggP : [128][256]   offset 0      (agg partial sums per 64-row chunk)
// zrP  : [7][4][256]  offset 32768  (matvec partials: m*4+q; m:0=Wxz 1=Whz 2=Cz 3=Wxr 4=Whr 5=Cr 6=Wxh)
#define WS_AGGP 0
#define WS_ZRP  32768

// A: agg partials. 128 blocks x 256 threads; block b owns rows [b*64, b*64+64).
// Vectorized: thread (g = t>>6, c = t&63) accumulates f32x4 of columns c*4..c*4+3
// over rows r = it*4+g; 16 fully-unrolled iterations put the whole 8.4 MB H read in flight.
__global__ void __launch_bounds__(256) k_agg(
        const float* __restrict__ E, const float* __restrict__ H,
        const int* __restrict__ dh, const int* __restrict__ dt,
        float* __restrict__ aggP) {
    __shared__ float e_sh[64];
    __shared__ f32x4 red[4][64];
    const int head = dh[0], tail = dt[0];
    const int t = threadIdx.x;
    const int i0 = blockIdx.x * 64;
    if (t < 64) {
        const int i = i0 + t;
        float e = 0.5f * E[(size_t)head * NN + i];
        if (head != tail) e += 0.5f * E[(size_t)tail * NN + i];
        if (i == tail) e += 0.5f;
        e_sh[t] = e;
    }
    __syncthreads();
    const int g = t >> 6, c = (t & 63) << 2;
    f32x4 acc = {0.f, 0.f, 0.f, 0.f};
    #pragma unroll
    for (int it = 0; it < 16; ++it) {
        const int r = it * 4 + g;
        const f32x4 hv = *(const f32x4*)(H + (size_t)(i0 + r) * CC + c);
        acc += hv * e_sh[r];
    }
    red[g][t & 63] = acc;
    __syncthreads();
    if (g == 0) {
        const f32x4 s = red[0][t] + red[1][t] + red[2][t] + red[3][t];
        *(f32x4*)(aggP + blockIdx.x * CC + (t << 2)) = s;
    }
}

// B: 7 matvec partial sets (all except Whh, which needs R). 28 blocks (m=0..6, q=0..3) x 256.
__global__ void __launch_bounds__(256) k_mv(
        const float* __restrict__ X, const float* __restrict__ H,
        const int* __restrict__ dh,
        const float* __restrict__ Wxz, const float* __restrict__ Whz,
        const float* __restrict__ Cz,  const float* __restrict__ Wxr,
        const float* __restrict__ Whr, const float* __restrict__ Cr,
        const float* __restrict__ Wxh,
        const float* __restrict__ aggP, float* __restrict__ zrP) {
    __shared__ float v_sh[64];
    const int m = blockIdx.x >> 2, q = blockIdx.x & 3;
    const int t = threadIdx.x;
    const float* W;
    switch (m) {
        case 0: W = Wxz; break; case 1: W = Whz; break; case 2: W = Cz; break;
        case 3: W = Wxr; break; case 4: W = Whr; break; case 5: W = Cr; break;
        default: W = Wxh; break;
    }
    if (t < 64) {
        const int k = q * 64 + t;
        float v;
        if (m == 1 || m == 4)      v = H[(size_t)dh[0] * CC + k];
        else if (m == 2 || m == 5) { v = 0.f; for (int b = 0; b < 128; ++b) v += aggP[b * CC + k]; }
        else                       v = X[k];
        v_sh[t] = v;
    }
    __syncthreads();
    float acc = 0.f;
    #pragma unroll
    for (int kk = 0; kk < 64; ++kk)
        acc += v_sh[kk] * W[(size_t)(q * 64 + kk) * CC + t];
    zrP[(m * 4 + q) * CC + t] = acc;
}

// C: big streaming kernel. Block 0 = GRU epilogue (Z, R, rs, Whh matvec, H~, head row of
// H_new) — its latency-bound 256 KB Whh read hides under the 90 µs of streaming by
// blocks 1..gridDim-1 (E_new + bulk H copy, head row skipped, nontemporal).
__global__ void __launch_bounds__(256) k_big(
        const float* __restrict__ E, const float* __restrict__ H,
        const int* __restrict__ dh, const int* __restrict__ dt,
        const float* __restrict__ bz, const float* __restrict__ br,
        const float* __restrict__ bh, const float* __restrict__ Whh,
        const float* __restrict__ zrP, float* __restrict__ out) {
    const int head = dh[0], tail = dt[0];
    const size_t nn = (size_t)NN * NN;

    if (blockIdx.x == 0) {
        __shared__ float rs_sh[CC];
        const int c = threadIdx.x;
        float sz = bz[c], sr = br[c];
        #pragma unroll
        for (int p = 0; p < 12; ++p)  sz += zrP[p * CC + c];
        #pragma unroll
        for (int p = 12; p < 24; ++p) sr += zrP[p * CC + c];
        const float z = 1.f / (1.f + expf(-sz));
        const float r = 1.f / (1.f + expf(-sr));
        const float h = H[(size_t)head * CC + c];
        rs_sh[c] = h * r;
        __syncthreads();
        float acc = 0.f;
        #pragma unroll 16
        for (int k = 0; k < CC; ++k)
            acc += rs_sh[k] * Whh[(size_t)k * CC + c];
        float s = bh[c] + acc;
        #pragma unroll
        for (int p = 24; p < 28; ++p) s += zrP[p * CC + c];
        const float ht = tanhf(s);
        out[nn + (size_t)head * CC + c] = z * h + (1.f - z) * ht;
        return;
    }

    const size_t total4 = (nn + (size_t)NN * CC) >> 2;
    const size_t nstream = (size_t)(gridDim.x - 1) * blockDim.x;
    for (size_t idx = (size_t)(blockIdx.x - 1) * blockDim.x + threadIdx.x;
         idx < total4; idx += nstream) {
        const size_t e = idx << 2;
        if (e < nn) {
            const f32x4 v = __builtin_nontemporal_load((const f32x4*)(E + e));
            f32x4 o = v * 0.5f;
            const int i = (int)(e >> LOG2N);
            if (i == head) {
                const int j = (int)(e & (NN - 1));
                if (head != tail) {
                    const f32x4 w = *(const f32x4*)(E + (size_t)tail * NN + j);
                    o += w * 0.5f;
                }
                if (tail >= j && tail < j + 4) o[tail - j] += 0.5f;
            }
            __builtin_nontemporal_store(o, (f32x4*)(out + e));
        } else {
            const size_t tt = e - nn;
            if ((int)(tt >> 8) != head) {
                const f32x4 hv = __builtin_nontemporal_load((const f32x4*)(H + tt));
                __builtin_nontemporal_store(hv, (f32x4*)(out + nn + tt));
            }
        }
    }
}

extern "C" void kernel_launch(void* const* d_in, const int* in_sizes, int n_in,
                              void* d_out, int out_size, void* d_ws, size_t ws_size,
                              hipStream_t stream) {
    const float* X    = (const float*)d_in[0];
    const int*   dh   = (const int*)d_in[1];
    const int*   dt   = (const int*)d_in[2];
    const float* E    = (const float*)d_in[3];
    const float* H    = (const float*)d_in[4];
    const float* Wxz  = (const float*)d_in[5];
    const float* Whz  = (const float*)d_in[6];
    const float* Cz   = (const float*)d_in[7];
    const float* bz   = (const float*)d_in[8];
    const float* Wxr  = (const float*)d_in[9];
    const float* Whr  = (const float*)d_in[10];
    const float* Cr   = (const float*)d_in[11];
    const float* br   = (const float*)d_in[12];
    const float* Wxh  = (const float*)d_in[13];
    const float* Whh  = (const float*)d_in[14];
    const float* bh   = (const float*)d_in[15];
    float* out = (float*)d_out;
    float* ws  = (float*)d_ws;

    float* aggP = ws + WS_AGGP;
    float* zrP  = ws + WS_ZRP;

    k_agg<<<128, 256, 0, stream>>>(E, H, dh, dt, aggP);
    k_mv<<<28, 256, 0, stream>>>(X, H, dh, Wxz, Whz, Cz, Wxr, Whr, Cr, Wxh, aggP, zrP);
    k_big<<<2049, 256, 0, stream>>>(E, H, dh, dt, bz, br, bh, Whh, zrP, out);
}

// Round 4
// 105.552 us; speedup vs baseline: 1.0810x; 1.0810x over previous
//
#include <hip/hip_runtime.h>
#include <math.h>

#define NN 8192
#define CC 256
#define LOG2N 13

typedef float f32x4 __attribute__((ext_vector_type(4)));

// ---------------- ws layout (floats) ----------------
// aggP : [128][256]   offset 0      (agg partial sums per 64-row chunk)
// zrP  : [7][4][256]  offset 32768  (matvec partials: m*4+q; m:0=Wxz 1=Whz 2=Cz 3=Wxr 4=Whr 5=Cr 6=Wxh)
#define WS_AGGP 0
#define WS_ZRP  32768

// A: agg partials. 128 blocks x 256 threads; block b owns rows [b*64, b*64+64).
__global__ void __launch_bounds__(256) k_agg(
        const float* __restrict__ E, const float* __restrict__ H,
        const int* __restrict__ dh, const int* __restrict__ dt,
        float* __restrict__ aggP) {
    __shared__ float e_sh[64];
    __shared__ f32x4 red[4][64];
    const int head = dh[0], tail = dt[0];
    const int t = threadIdx.x;
    const int i0 = blockIdx.x * 64;
    if (t < 64) {
        const int i = i0 + t;
        float e = 0.5f * E[(size_t)head * NN + i];
        if (head != tail) e += 0.5f * E[(size_t)tail * NN + i];
        if (i == tail) e += 0.5f;
        e_sh[t] = e;
    }
    __syncthreads();
    const int g = t >> 6, c = (t & 63) << 2;
    f32x4 acc = {0.f, 0.f, 0.f, 0.f};
    #pragma unroll
    for (int it = 0; it < 16; ++it) {
        const int r = it * 4 + g;
        const f32x4 hv = *(const f32x4*)(H + (size_t)(i0 + r) * CC + c);
        acc += hv * e_sh[r];
    }
    red[g][t & 63] = acc;
    __syncthreads();
    if (g == 0) {
        const f32x4 s = red[0][t] + red[1][t] + red[2][t] + red[3][t];
        *(f32x4*)(aggP + blockIdx.x * CC + (t << 2)) = s;
    }
}

// B: 7 matvec partial sets (all except Whh, which needs R). 28 blocks (m=0..6, q=0..3) x 256.
__global__ void __launch_bounds__(256) k_mv(
        const float* __restrict__ X, const float* __restrict__ H,
        const int* __restrict__ dh,
        const float* __restrict__ Wxz, const float* __restrict__ Whz,
        const float* __restrict__ Cz,  const float* __restrict__ Wxr,
        const float* __restrict__ Whr, const float* __restrict__ Cr,
        const float* __restrict__ Wxh,
        const float* __restrict__ aggP, float* __restrict__ zrP) {
    __shared__ float v_sh[64];
    const int m = blockIdx.x >> 2, q = blockIdx.x & 3;
    const int t = threadIdx.x;
    const float* W;
    switch (m) {
        case 0: W = Wxz; break; case 1: W = Whz; break; case 2: W = Cz; break;
        case 3: W = Wxr; break; case 4: W = Whr; break; case 5: W = Cr; break;
        default: W = Wxh; break;
    }
    if (t < 64) {
        const int k = q * 64 + t;
        float v;
        if (m == 1 || m == 4)      v = H[(size_t)dh[0] * CC + k];
        else if (m == 2 || m == 5) { v = 0.f; for (int b = 0; b < 128; ++b) v += aggP[b * CC + k]; }
        else                       v = X[k];
        v_sh[t] = v;
    }
    __syncthreads();
    float acc = 0.f;
    #pragma unroll
    for (int kk = 0; kk < 64; ++kk)
        acc += v_sh[kk] * W[(size_t)(q * 64 + kk) * CC + t];
    zrP[(m * 4 + q) * CC + t] = acc;
}

// C: big streaming kernel. Block 0 = GRU epilogue; blocks 1.. stream E_new + H copy.
// nt LOADS (protect caches from the 545 MB read stream), NORMAL stores (write-back
// L2 write-combining — the 6.9 TB/s fill and 6.29 TB/s copy ceilings use this path).
// Manual 2x unroll: both loads issued before both stores for 2x memory-level parallelism.
__global__ void __launch_bounds__(256) k_big(
        const float* __restrict__ E, const float* __restrict__ H,
        const int* __restrict__ dh, const int* __restrict__ dt,
        const float* __restrict__ bz, const float* __restrict__ br,
        const float* __restrict__ bh, const float* __restrict__ Whh,
        const float* __restrict__ zrP, float* __restrict__ out) {
    const int head = dh[0], tail = dt[0];
    const size_t nn = (size_t)NN * NN;

    if (blockIdx.x == 0) {
        __shared__ float rs_sh[CC];
        const int c = threadIdx.x;
        float sz = bz[c], sr = br[c];
        #pragma unroll
        for (int p = 0; p < 12; ++p)  sz += zrP[p * CC + c];
        #pragma unroll
        for (int p = 12; p < 24; ++p) sr += zrP[p * CC + c];
        const float z = 1.f / (1.f + expf(-sz));
        const float r = 1.f / (1.f + expf(-sr));
        const float h = H[(size_t)head * CC + c];
        rs_sh[c] = h * r;
        __syncthreads();
        float acc = 0.f;
        #pragma unroll 16
        for (int k = 0; k < CC; ++k)
            acc += rs_sh[k] * Whh[(size_t)k * CC + c];
        float s = bh[c] + acc;
        #pragma unroll
        for (int p = 24; p < 28; ++p) s += zrP[p * CC + c];
        const float ht = tanhf(s);
        out[nn + (size_t)head * CC + c] = z * h + (1.f - z) * ht;
        return;
    }

    const size_t total4 = (nn + (size_t)NN * CC) >> 2;
    const size_t step = (size_t)(gridDim.x - 1) * blockDim.x;

    auto load_elem = [&](size_t idx) -> f32x4 {
        const size_t e = idx << 2;
        if (e < nn) return __builtin_nontemporal_load((const f32x4*)(E + e));
        return __builtin_nontemporal_load((const f32x4*)(H + (e - nn)));
    };
    auto compute_store = [&](size_t idx, f32x4 v) {
        const size_t e = idx << 2;
        if (e < nn) {
            f32x4 o = v * 0.5f;
            const int i = (int)(e >> LOG2N);
            if (i == head) {
                const int j = (int)(e & (NN - 1));
                if (head != tail) {
                    const f32x4 w = *(const f32x4*)(E + (size_t)tail * NN + j);
                    o += w * 0.5f;
                }
                if (tail >= j && tail < j + 4) o[tail - j] += 0.5f;
            }
            *(f32x4*)(out + e) = o;
        } else {
            const size_t tt = e - nn;
            if ((int)(tt >> 8) != head)
                *(f32x4*)(out + nn + tt) = v;
        }
    };

    for (size_t idx = (size_t)(blockIdx.x - 1) * blockDim.x + threadIdx.x;
         idx < total4; idx += 2 * step) {
        const size_t idx2 = idx + step;
        const bool ok2 = idx2 < total4;
        const f32x4 a = load_elem(idx);
        f32x4 b = {0.f, 0.f, 0.f, 0.f};
        if (ok2) b = load_elem(idx2);
        compute_store(idx, a);
        if (ok2) compute_store(idx2, b);
    }
}

extern "C" void kernel_launch(void* const* d_in, const int* in_sizes, int n_in,
                              void* d_out, int out_size, void* d_ws, size_t ws_size,
                              hipStream_t stream) {
    const float* X    = (const float*)d_in[0];
    const int*   dh   = (const int*)d_in[1];
    const int*   dt   = (const int*)d_in[2];
    const float* E    = (const float*)d_in[3];
    const float* H    = (const float*)d_in[4];
    const float* Wxz  = (const float*)d_in[5];
    const float* Whz  = (const float*)d_in[6];
    const float* Cz   = (const float*)d_in[7];
    const float* bz   = (const float*)d_in[8];
    const float* Wxr  = (const float*)d_in[9];
    const float* Whr  = (const float*)d_in[10];
    const float* Cr   = (const float*)d_in[11];
    const float* br   = (const float*)d_in[12];
    const float* Wxh  = (const float*)d_in[13];
    const float* Whh  = (const float*)d_in[14];
    const float* bh   = (const float*)d_in[15];
    float* out = (float*)d_out;
    float* ws  = (float*)d_ws;

    float* aggP = ws + WS_AGGP;
    float* zrP  = ws + WS_ZRP;

    k_agg<<<128, 256, 0, stream>>>(E, H, dh, dt, aggP);
    k_mv<<<28, 256, 0, stream>>>(X, H, dh, Wxz, Whz, Cz, Wxr, Whr, Cr, Wxh, aggP, zrP);
    k_big<<<2049, 256, 0, stream>>>(E, H, dh, dt, bz, br, bh, Whh, zrP, out);
}